// Round 1
// baseline (1711.575 us; speedup 1.0000x reference)
//
#include <hip/hip_runtime.h>
#include <math.h>

#define BATCH 4096
#define NF    2048

// ---------------------------------------------------------------------------
// Elementwise: h = sigmoid(x * sum(conv_w) + conv_b)
// ---------------------------------------------------------------------------
__global__ __launch_bounds__(256) void act_kernel(
    const float* __restrict__ x, const float* __restrict__ conv_w,
    const float* __restrict__ conv_b, float* __restrict__ h, int n4)
{
    const float s = conv_w[0] + conv_w[1] + conv_w[2] + conv_w[3];
    const float c = conv_b[0];
    int i = blockIdx.x * blockDim.x + threadIdx.x;
    if (i < n4) {
        float4 v = ((const float4*)x)[i];
        float4 r;
        r.x = 1.0f / (1.0f + expf(-(v.x * s + c)));
        r.y = 1.0f / (1.0f + expf(-(v.y * s + c)));
        r.z = 1.0f / (1.0f + expf(-(v.z * s + c)));
        r.w = 1.0f / (1.0f + expf(-(v.w * s + c)));
        ((float4*)h)[i] = r;
    }
}

// ---------------------------------------------------------------------------
// C = relu_opt(A @ W^T + bias)   A:(M,K) row-major, W:(N,K) row-major ("NT")
// 128x128 tile, BK=16, 256 threads, 8x8 outputs per thread.
// ---------------------------------------------------------------------------
#define BM 128
#define BN 128
#define BK 16
#define PAD 4   // row stride 132 floats: 2-way LDS write aliasing only (free)

__global__ __launch_bounds__(256) void gemm_bias_relu(
    const float* __restrict__ A, const float* __restrict__ W,
    const float* __restrict__ bias, float* __restrict__ C,
    int M, int N, int K, int do_relu)
{
    __shared__ float As[BK][BM + PAD];
    __shared__ float Bs[BK][BN + PAD];

    const int t  = threadIdx.x;
    const int bm = blockIdx.y * BM;
    const int bn = blockIdx.x * BN;

    const int tn = (t & 15) * 8;   // 0..120, n-fast within wave
    const int tm = (t >> 4) * 8;   // 0..120

    const int r0 = t >> 2;         // 0..63 : tile row for staging
    const int kv = (t & 3) << 2;   // 0,4,8,12 : k-offset (float4) for staging

    float acc[8][8] = {};

    for (int k0 = 0; k0 < K; k0 += BK) {
        #pragma unroll
        for (int half = 0; half < 2; ++half) {
            const int row = r0 + half * 64;
            float4 av = *(const float4*)&A[(size_t)(bm + row) * K + k0 + kv];
            As[kv + 0][row] = av.x;
            As[kv + 1][row] = av.y;
            As[kv + 2][row] = av.z;
            As[kv + 3][row] = av.w;
            float4 bv = *(const float4*)&W[(size_t)(bn + row) * K + k0 + kv];
            Bs[kv + 0][row] = bv.x;
            Bs[kv + 1][row] = bv.y;
            Bs[kv + 2][row] = bv.z;
            Bs[kv + 3][row] = bv.w;
        }
        __syncthreads();

        #pragma unroll
        for (int kk = 0; kk < BK; ++kk) {
            float a[8], b[8];
            *(float4*)&a[0] = *(const float4*)&As[kk][tm];
            *(float4*)&a[4] = *(const float4*)&As[kk][tm + 4];
            *(float4*)&b[0] = *(const float4*)&Bs[kk][tn];
            *(float4*)&b[4] = *(const float4*)&Bs[kk][tn + 4];
            #pragma unroll
            for (int i = 0; i < 8; ++i)
                #pragma unroll
                for (int j = 0; j < 8; ++j)
                    acc[i][j] = fmaf(a[i], b[j], acc[i][j]);
        }
        __syncthreads();
    }

    #pragma unroll
    for (int i = 0; i < 8; ++i) {
        const int row = bm + tm + i;
        #pragma unroll
        for (int j = 0; j < 8; j += 4) {
            float4 v;
            v.x = acc[i][j + 0] + bias[bn + tn + j + 0];
            v.y = acc[i][j + 1] + bias[bn + tn + j + 1];
            v.z = acc[i][j + 2] + bias[bn + tn + j + 2];
            v.w = acc[i][j + 3] + bias[bn + tn + j + 3];
            if (do_relu) {
                v.x = fmaxf(v.x, 0.0f);
                v.y = fmaxf(v.y, 0.0f);
                v.z = fmaxf(v.z, 0.0f);
                v.w = fmaxf(v.w, 0.0f);
            }
            *(float4*)&C[(size_t)row * N + bn + tn + j] = v;
        }
    }
}

// ---------------------------------------------------------------------------
// Head: out[b, j] = dot(h[b,:], Wh[j,:]) + bh[j],  j in {0,1}
// One wave per row, 4 rows per 256-thread block.
// ---------------------------------------------------------------------------
__global__ __launch_bounds__(256) void head_kernel(
    const float* __restrict__ h, const float* __restrict__ Wh,
    const float* __restrict__ bh, float* __restrict__ out)
{
    const int wave = threadIdx.x >> 6;
    const int lane = threadIdx.x & 63;
    const int row  = blockIdx.x * 4 + wave;
    const float* hr = h + (size_t)row * NF;

    float acc0 = 0.0f, acc1 = 0.0f;
    for (int k = lane * 4; k < NF; k += 64 * 4) {
        float4 v  = *(const float4*)&hr[k];
        float4 w0 = *(const float4*)&Wh[k];
        float4 w1 = *(const float4*)&Wh[NF + k];
        acc0 += v.x * w0.x + v.y * w0.y + v.z * w0.z + v.w * w0.w;
        acc1 += v.x * w1.x + v.y * w1.y + v.z * w1.z + v.w * w1.w;
    }
    #pragma unroll
    for (int off = 32; off > 0; off >>= 1) {
        acc0 += __shfl_down(acc0, off, 64);
        acc1 += __shfl_down(acc1, off, 64);
    }
    if (lane == 0) {
        out[row * 2 + 0] = acc0 + bh[0];
        out[row * 2 + 1] = acc1 + bh[1];
    }
}

// ---------------------------------------------------------------------------
extern "C" void kernel_launch(void* const* d_in, const int* in_sizes, int n_in,
                              void* d_out, int out_size, void* d_ws, size_t ws_size,
                              hipStream_t stream)
{
    const float* x      = (const float*)d_in[0];
    const float* conv_w = (const float*)d_in[1];
    const float* conv_b = (const float*)d_in[2];
    const float* W0     = (const float*)d_in[3];
    const float* b0     = (const float*)d_in[4];
    const float* W1     = (const float*)d_in[5];
    const float* b1     = (const float*)d_in[6];
    const float* W2     = (const float*)d_in[7];
    const float* b2     = (const float*)d_in[8];
    const float* W3     = (const float*)d_in[9];
    const float* b3     = (const float*)d_in[10];
    const float* Wh     = (const float*)d_in[11];
    const float* bh     = (const float*)d_in[12];
    float* out = (float*)d_out;

    const size_t buf_elems = (size_t)BATCH * NF;
    float* ws0 = (float*)d_ws;
    float* ws1 = ws0 + buf_elems;

    // 1) h0 = sigmoid(x * sum(conv_w) + conv_b)
    {
        int n4 = (BATCH * NF) / 4;
        act_kernel<<<(n4 + 255) / 256, 256, 0, stream>>>(x, conv_w, conv_b, ws0, n4);
    }

    // 2) four hidden layers
    dim3 grid(NF / BN, BATCH / BM);
    gemm_bias_relu<<<grid, 256, 0, stream>>>(ws0, W0, b0, ws1, BATCH, NF, NF, 1);
    gemm_bias_relu<<<grid, 256, 0, stream>>>(ws1, W1, b1, ws0, BATCH, NF, NF, 1);
    gemm_bias_relu<<<grid, 256, 0, stream>>>(ws0, W2, b2, ws1, BATCH, NF, NF, 1);
    gemm_bias_relu<<<grid, 256, 0, stream>>>(ws1, W3, b3, ws0, BATCH, NF, NF, 1);

    // 3) head
    head_kernel<<<BATCH / 4, 256, 0, stream>>>(ws0, Wh, bh, out);
}

// Round 2
// 682.241 us; speedup vs baseline: 2.5088x; 2.5088x over previous
//
#include <hip/hip_runtime.h>
#include <math.h>

#define BATCH 4096
#define NF    2048

typedef unsigned short u16;
typedef unsigned int   u32;
typedef __attribute__((ext_vector_type(8))) short  short8;   // 8 bf16 = 4 VGPR
typedef __attribute__((ext_vector_type(4))) float  floatx4;  // MFMA C/D

// ---------------------------------------------------------------------------
// bf16 helpers (RNE)
// ---------------------------------------------------------------------------
__device__ __forceinline__ u16 f2bf(float f) {
    u32 u = __builtin_bit_cast(u32, f);
    u += 0x7fffu + ((u >> 16) & 1u);
    return (u16)(u >> 16);
}
__device__ __forceinline__ float bf2f(u16 h) {
    u32 u = ((u32)h) << 16;
    return __builtin_bit_cast(float, u);
}

// ---------------------------------------------------------------------------
// h = sigmoid(x*sum(conv_w)+conv_b), written in split-bf16 (hi+lo) form
// ---------------------------------------------------------------------------
__global__ __launch_bounds__(256) void act_split_kernel(
    const float* __restrict__ x, const float* __restrict__ cw,
    const float* __restrict__ cb, u16* __restrict__ hhi, u16* __restrict__ hlo,
    int n4)
{
    const float s = cw[0] + cw[1] + cw[2] + cw[3];
    const float c = cb[0];
    int i = blockIdx.x * blockDim.x + threadIdx.x;
    if (i < n4) {
        float4 v = ((const float4*)x)[i];
        float vv[4] = {v.x, v.y, v.z, v.w};
        ushort4 h4, l4;
        u16 h[4], l[4];
        #pragma unroll
        for (int j = 0; j < 4; ++j) {
            float r = 1.0f / (1.0f + expf(-(vv[j] * s + c)));
            h[j] = f2bf(r);
            l[j] = f2bf(r - bf2f(h[j]));
        }
        h4.x = h[0]; h4.y = h[1]; h4.z = h[2]; h4.w = h[3];
        l4.x = l[0]; l4.y = l[1]; l4.z = l[2]; l4.w = l[3];
        *(ushort4*)&hhi[i * 4] = h4;
        *(ushort4*)&hlo[i * 4] = l4;
    }
}

// ---------------------------------------------------------------------------
// Split fp32 weights into bf16 hi+lo
// ---------------------------------------------------------------------------
__global__ __launch_bounds__(256) void split_w_kernel(
    const float* __restrict__ w, u16* __restrict__ whi, u16* __restrict__ wlo,
    int n4)
{
    int i = blockIdx.x * blockDim.x + threadIdx.x;
    if (i < n4) {
        float4 v = ((const float4*)w)[i];
        float vv[4] = {v.x, v.y, v.z, v.w};
        ushort4 h4, l4;
        u16 h[4], l[4];
        #pragma unroll
        for (int j = 0; j < 4; ++j) {
            h[j] = f2bf(vv[j]);
            l[j] = f2bf(vv[j] - bf2f(h[j]));
        }
        h4.x = h[0]; h4.y = h[1]; h4.z = h[2]; h4.w = h[3];
        l4.x = l[0]; l4.y = l[1]; l4.z = l[2]; l4.w = l[3];
        *(ushort4*)&whi[i * 4] = h4;
        *(ushort4*)&wlo[i * 4] = l4;
    }
}

// ---------------------------------------------------------------------------
// Split-bf16 MFMA GEMM: C = relu(A @ W^T + bias), C re-split to hi/lo bf16.
// A:(M,K) split hi/lo bf16, W:(N,K) split hi/lo bf16.
// 128x128 tile, BK=32, 256 threads = 2x2 waves, each wave 4x4 of 16x16x32.
// LDS layout per tile: [rowblock 8][quad 4][row 16][8 bf16] so that
//   - global_load_lds lane-sequential writes are contiguous (HW requirement)
//   - ds_read_b128 fragment reads are 2-way bank aliasing only (free)
// ---------------------------------------------------------------------------
#define BM 128
#define BN 128
#define BK 32

__device__ __forceinline__ void stage16(const u16* g, u16* l) {
    __builtin_amdgcn_global_load_lds(
        (const __attribute__((address_space(1))) u32*)g,
        (__attribute__((address_space(3))) u32*)l, 16, 0, 0);
}

__global__ __launch_bounds__(256) void gemm_split_bf16(
    const u16* __restrict__ Ah, const u16* __restrict__ Al,
    const u16* __restrict__ Bh, const u16* __restrict__ Bl,
    const float* __restrict__ bias,
    u16* __restrict__ Ch, u16* __restrict__ Cl,
    int M, int N, int K)
{
    __shared__ u16 sAh[BM * BK];
    __shared__ u16 sAl[BM * BK];
    __shared__ u16 sBh[BN * BK];
    __shared__ u16 sBl[BN * BK];

    const int t    = threadIdx.x;
    const int wv   = t >> 6;        // wave 0..3
    const int ln   = t & 63;
    const int quad = ln >> 4;       // 0..3
    const int ml   = ln & 15;       // 0..15
    const int wm   = wv >> 1;       // 2x2 wave grid
    const int wn   = wv & 1;
    const int bm   = blockIdx.y * BM;
    const int bn   = blockIdx.x * BN;

    floatx4 zero = {0.f, 0.f, 0.f, 0.f};
    floatx4 acc[4][4];
    #pragma unroll
    for (int i = 0; i < 4; ++i)
        #pragma unroll
        for (int j = 0; j < 4; ++j) acc[i][j] = zero;

    for (int k0 = 0; k0 < K; k0 += BK) {
        // ---- stage A/B hi+lo tiles: each wave-call moves 16 rows x 32 k ----
        #pragma unroll
        for (int cs = 0; cs < 2; ++cs) {
            const int rb   = cs * 4 + wv;           // rowblock 0..7
            const int row  = rb * 16 + ml;          // per-lane global row
            const size_t ga = (size_t)(bm + row) * K + k0 + quad * 8;
            const size_t gb = (size_t)(bn + row) * K + k0 + quad * 8;
            const int lo   = rb * 512;              // u16 offset, wave-uniform
            stage16(Ah + ga, &sAh[lo]);
            stage16(Al + ga, &sAl[lo]);
            stage16(Bh + gb, &sBh[lo]);
            stage16(Bl + gb, &sBl[lo]);
        }
        __syncthreads();

        // ---- fragments: A[m=ln&15][k=quad*8+j], B likewise from W rows ----
        short8 ah[4], al[4], bh[4], bl[4];
        #pragma unroll
        for (int i = 0; i < 4; ++i) {
            const int ra = (wm * 4 + i) * 512 + quad * 128 + ml * 8;
            const int rb = (wn * 4 + i) * 512 + quad * 128 + ml * 8;
            ah[i] = *(const short8*)&sAh[ra];
            al[i] = *(const short8*)&sAl[ra];
            bh[i] = *(const short8*)&sBh[rb];
            bl[i] = *(const short8*)&sBl[rb];
        }

        #pragma unroll
        for (int i = 0; i < 4; ++i)
            #pragma unroll
            for (int j = 0; j < 4; ++j) {
                acc[i][j] = __builtin_amdgcn_mfma_f32_16x16x32_bf16(ah[i], bh[j], acc[i][j], 0, 0, 0);
                acc[i][j] = __builtin_amdgcn_mfma_f32_16x16x32_bf16(ah[i], bl[j], acc[i][j], 0, 0, 0);
                acc[i][j] = __builtin_amdgcn_mfma_f32_16x16x32_bf16(al[i], bh[j], acc[i][j], 0, 0, 0);
            }
        __syncthreads();
    }

    // ---- epilogue: bias + relu + re-split; C/D map: n=ln&15, m=quad*4+r ----
    #pragma unroll
    for (int j = 0; j < 4; ++j) {
        const int n  = bn + wn * 64 + j * 16 + ml;
        const float bv = bias[n];
        #pragma unroll
        for (int i = 0; i < 4; ++i) {
            #pragma unroll
            for (int r = 0; r < 4; ++r) {
                const int m = bm + wm * 64 + i * 16 + quad * 4 + r;
                float v = acc[i][j][r] + bv;
                v = fmaxf(v, 0.0f);
                u16 h = f2bf(v);
                Ch[(size_t)m * N + n] = h;
                Cl[(size_t)m * N + n] = f2bf(v - bf2f(h));
            }
        }
    }
}

// ---------------------------------------------------------------------------
// Head: out[b,j] = dot(h[b,:], Wh[j,:]) + bh[j], h reconstructed from hi+lo
// ---------------------------------------------------------------------------
__global__ __launch_bounds__(256) void head_split_kernel(
    const u16* __restrict__ hh, const u16* __restrict__ hl,
    const float* __restrict__ Wh, const float* __restrict__ bh,
    float* __restrict__ out)
{
    const int wave = threadIdx.x >> 6;
    const int lane = threadIdx.x & 63;
    const int row  = blockIdx.x * 4 + wave;
    const u16* ph = hh + (size_t)row * NF;
    const u16* pl = hl + (size_t)row * NF;

    float acc0 = 0.0f, acc1 = 0.0f;
    for (int k = lane * 4; k < NF; k += 256) {
        ushort4 h4 = *(const ushort4*)&ph[k];
        ushort4 l4 = *(const ushort4*)&pl[k];
        float4 w0 = *(const float4*)&Wh[k];
        float4 w1 = *(const float4*)&Wh[NF + k];
        float v0 = bf2f(h4.x) + bf2f(l4.x);
        float v1 = bf2f(h4.y) + bf2f(l4.y);
        float v2 = bf2f(h4.z) + bf2f(l4.z);
        float v3 = bf2f(h4.w) + bf2f(l4.w);
        acc0 += v0 * w0.x + v1 * w0.y + v2 * w0.z + v3 * w0.w;
        acc1 += v0 * w1.x + v1 * w1.y + v2 * w1.z + v3 * w1.w;
    }
    #pragma unroll
    for (int off = 32; off > 0; off >>= 1) {
        acc0 += __shfl_down(acc0, off, 64);
        acc1 += __shfl_down(acc1, off, 64);
    }
    if (lane == 0) {
        out[row * 2 + 0] = acc0 + bh[0];
        out[row * 2 + 1] = acc1 + bh[1];
    }
}

// ===========================================================================
// fp32 fallback path (round-1 kernels) — used only if ws_size < 80 MB
// ===========================================================================
__global__ __launch_bounds__(256) void act_kernel_f32(
    const float* __restrict__ x, const float* __restrict__ conv_w,
    const float* __restrict__ conv_b, float* __restrict__ h, int n4)
{
    const float s = conv_w[0] + conv_w[1] + conv_w[2] + conv_w[3];
    const float c = conv_b[0];
    int i = blockIdx.x * blockDim.x + threadIdx.x;
    if (i < n4) {
        float4 v = ((const float4*)x)[i];
        float4 r;
        r.x = 1.0f / (1.0f + expf(-(v.x * s + c)));
        r.y = 1.0f / (1.0f + expf(-(v.y * s + c)));
        r.z = 1.0f / (1.0f + expf(-(v.z * s + c)));
        r.w = 1.0f / (1.0f + expf(-(v.w * s + c)));
        ((float4*)h)[i] = r;
    }
}

#define FBM 128
#define FBN 128
#define FBK 16
#define FPAD 4

__global__ __launch_bounds__(256) void gemm_bias_relu_f32(
    const float* __restrict__ A, const float* __restrict__ W,
    const float* __restrict__ bias, float* __restrict__ C,
    int M, int N, int K, int do_relu)
{
    __shared__ float As[FBK][FBM + FPAD];
    __shared__ float Bs[FBK][FBN + FPAD];
    const int t  = threadIdx.x;
    const int bm = blockIdx.y * FBM;
    const int bn = blockIdx.x * FBN;
    const int tn = (t & 15) * 8;
    const int tm = (t >> 4) * 8;
    const int r0 = t >> 2;
    const int kv = (t & 3) << 2;
    float acc[8][8] = {};
    for (int k0 = 0; k0 < K; k0 += FBK) {
        #pragma unroll
        for (int half = 0; half < 2; ++half) {
            const int row = r0 + half * 64;
            float4 av = *(const float4*)&A[(size_t)(bm + row) * K + k0 + kv];
            As[kv + 0][row] = av.x; As[kv + 1][row] = av.y;
            As[kv + 2][row] = av.z; As[kv + 3][row] = av.w;
            float4 bv = *(const float4*)&W[(size_t)(bn + row) * K + k0 + kv];
            Bs[kv + 0][row] = bv.x; Bs[kv + 1][row] = bv.y;
            Bs[kv + 2][row] = bv.z; Bs[kv + 3][row] = bv.w;
        }
        __syncthreads();
        #pragma unroll
        for (int kk = 0; kk < FBK; ++kk) {
            float a[8], b[8];
            *(float4*)&a[0] = *(const float4*)&As[kk][tm];
            *(float4*)&a[4] = *(const float4*)&As[kk][tm + 4];
            *(float4*)&b[0] = *(const float4*)&Bs[kk][tn];
            *(float4*)&b[4] = *(const float4*)&Bs[kk][tn + 4];
            #pragma unroll
            for (int i = 0; i < 8; ++i)
                #pragma unroll
                for (int j = 0; j < 8; ++j)
                    acc[i][j] = fmaf(a[i], b[j], acc[i][j]);
        }
        __syncthreads();
    }
    #pragma unroll
    for (int i = 0; i < 8; ++i) {
        const int row = bm + tm + i;
        #pragma unroll
        for (int j = 0; j < 8; j += 4) {
            float4 v;
            v.x = acc[i][j + 0] + bias[bn + tn + j + 0];
            v.y = acc[i][j + 1] + bias[bn + tn + j + 1];
            v.z = acc[i][j + 2] + bias[bn + tn + j + 2];
            v.w = acc[i][j + 3] + bias[bn + tn + j + 3];
            if (do_relu) {
                v.x = fmaxf(v.x, 0.0f); v.y = fmaxf(v.y, 0.0f);
                v.z = fmaxf(v.z, 0.0f); v.w = fmaxf(v.w, 0.0f);
            }
            *(float4*)&C[(size_t)row * N + bn + tn + j] = v;
        }
    }
}

__global__ __launch_bounds__(256) void head_kernel_f32(
    const float* __restrict__ h, const float* __restrict__ Wh,
    const float* __restrict__ bh, float* __restrict__ out)
{
    const int wave = threadIdx.x >> 6;
    const int lane = threadIdx.x & 63;
    const int row  = blockIdx.x * 4 + wave;
    const float* hr = h + (size_t)row * NF;
    float acc0 = 0.0f, acc1 = 0.0f;
    for (int k = lane * 4; k < NF; k += 256) {
        float4 v  = *(const float4*)&hr[k];
        float4 w0 = *(const float4*)&Wh[k];
        float4 w1 = *(const float4*)&Wh[NF + k];
        acc0 += v.x * w0.x + v.y * w0.y + v.z * w0.z + v.w * w0.w;
        acc1 += v.x * w1.x + v.y * w1.y + v.z * w1.z + v.w * w1.w;
    }
    #pragma unroll
    for (int off = 32; off > 0; off >>= 1) {
        acc0 += __shfl_down(acc0, off, 64);
        acc1 += __shfl_down(acc1, off, 64);
    }
    if (lane == 0) {
        out[row * 2 + 0] = acc0 + bh[0];
        out[row * 2 + 1] = acc1 + bh[1];
    }
}

// ---------------------------------------------------------------------------
extern "C" void kernel_launch(void* const* d_in, const int* in_sizes, int n_in,
                              void* d_out, int out_size, void* d_ws, size_t ws_size,
                              hipStream_t stream)
{
    const float* x      = (const float*)d_in[0];
    const float* conv_w = (const float*)d_in[1];
    const float* conv_b = (const float*)d_in[2];
    const float* Ws[4]  = {(const float*)d_in[3], (const float*)d_in[5],
                           (const float*)d_in[7], (const float*)d_in[9]};
    const float* bs[4]  = {(const float*)d_in[4], (const float*)d_in[6],
                           (const float*)d_in[8], (const float*)d_in[10]};
    const float* Wh     = (const float*)d_in[11];
    const float* bh     = (const float*)d_in[12];
    float* out = (float*)d_out;

    const size_t act_elems = (size_t)BATCH * NF;  // u16 elements per buffer
    const size_t w_elems   = (size_t)NF * NF;
    const size_t need = (4 * act_elems + 2 * w_elems) * sizeof(u16);  // 80 MB

    if (ws_size >= need) {
        u16* a0h = (u16*)d_ws;
        u16* a0l = a0h + act_elems;
        u16* a1h = a0l + act_elems;
        u16* a1l = a1h + act_elems;
        u16* wh  = a1l + act_elems;
        u16* wl  = wh + w_elems;

        int n4 = (BATCH * NF) / 4;
        act_split_kernel<<<(n4 + 255) / 256, 256, 0, stream>>>(
            x, conv_w, conv_b, a0h, a0l, n4);

        dim3 grid(NF / BN, BATCH / BM);
        u16 *inh = a0h, *inl = a0l, *outh = a1h, *outl = a1l;
        int nw4 = (NF * NF) / 4;
        for (int l = 0; l < 4; ++l) {
            split_w_kernel<<<(nw4 + 255) / 256, 256, 0, stream>>>(Ws[l], wh, wl, nw4);
            gemm_split_bf16<<<grid, 256, 0, stream>>>(
                inh, inl, wh, wl, bs[l], outh, outl, BATCH, NF, NF);
            u16* th = inh; u16* tl = inl;
            inh = outh; inl = outl; outh = th; outl = tl;
        }
        head_split_kernel<<<BATCH / 4, 256, 0, stream>>>(inh, inl, Wh, bh, out);
    } else {
        // fp32 fallback (needs 64 MB)
        float* ws0 = (float*)d_ws;
        float* ws1 = ws0 + act_elems;
        int n4 = (BATCH * NF) / 4;
        act_kernel_f32<<<(n4 + 255) / 256, 256, 0, stream>>>(x, conv_w, conv_b, ws0, n4);
        dim3 grid(NF / FBN, BATCH / FBM);
        gemm_bias_relu_f32<<<grid, 256, 0, stream>>>(ws0, Ws[0], bs[0], ws1, BATCH, NF, NF, 1);
        gemm_bias_relu_f32<<<grid, 256, 0, stream>>>(ws1, Ws[1], bs[1], ws0, BATCH, NF, NF, 1);
        gemm_bias_relu_f32<<<grid, 256, 0, stream>>>(ws0, Ws[2], bs[2], ws1, BATCH, NF, NF, 1);
        gemm_bias_relu_f32<<<grid, 256, 0, stream>>>(ws1, Ws[3], bs[3], ws0, BATCH, NF, NF, 1);
        head_kernel_f32<<<BATCH / 4, 256, 0, stream>>>(ws0, Wh, bh, out);
    }
}